// Round 2
// baseline (3924.887 us; speedup 1.0000x reference)
//
#include <hip/hip_runtime.h>
#include <hip/hip_bf16.h>

// Fused Llama layer: B=2 S=2048 H=2048 NH=16 HD=128 INTER=5504 R=16
#define B_ 2
#define S_ 2048
#define H_ 2048
#define NH_ 16
#define HD_ 128
#define INTER_ 5504
#define M_ (B_*S_)

using bf16x8 = __attribute__((ext_vector_type(8))) short;
using f32x4  = __attribute__((ext_vector_type(4))) float;

__device__ __forceinline__ float b2f(unsigned short u) {
  union { unsigned u; float f; } c; c.u = ((unsigned)u) << 16; return c.f;
}
__device__ __forceinline__ short f2b(float f) {
  union { float f; unsigned u; } c; c.f = f;
  unsigned r = (c.u + 0x7fffu + ((c.u >> 16) & 1u)) >> 16;
  return (short)r;
}

// ---------------- fp32 -> bf16 weight convert ----------------
__global__ void k_f2b(const float* __restrict__ in, short* __restrict__ out, int n) {
  int i = blockIdx.x * 256 + threadIdx.x;
  if (i < n) out[i] = f2b(in[i]);
}

// ---------------- RMSNorm (fp32 in, bf16 out) ----------------
__global__ __launch_bounds__(256) void k_rmsnorm(const float* __restrict__ x,
                                                 const float* __restrict__ w,
                                                 short* __restrict__ out) {
  int row = blockIdx.x;
  const float4* xr = (const float4*)(x + (long)row * H_);
  float ss = 0.f;
  float4 v[2];
#pragma unroll
  for (int it = 0; it < 2; ++it) {
    float4 t = xr[threadIdx.x + it * 256];
    v[it] = t;
    ss += t.x*t.x + t.y*t.y + t.z*t.z + t.w*t.w;
  }
#pragma unroll
  for (int o = 32; o; o >>= 1) ss += __shfl_xor(ss, o);
  __shared__ float s4[4];
  if ((threadIdx.x & 63) == 0) s4[threadIdx.x >> 6] = ss;
  __syncthreads();
  float r = rsqrtf((s4[0] + s4[1] + s4[2] + s4[3]) * (1.f / H_) + 1e-5f);
  const float4* wr = (const float4*)w;
  short4* orow = (short4*)(out + (long)row * H_);
#pragma unroll
  for (int it = 0; it < 2; ++it) {
    float4 t = v[it];
    float4 ww = wr[threadIdx.x + it * 256];
    short4 o4;
    o4.x = f2b(t.x * r * ww.x); o4.y = f2b(t.y * r * ww.y);
    o4.z = f2b(t.z * r * ww.z); o4.w = f2b(t.w * r * ww.w);
    orow[threadIdx.x + it * 256] = o4;
  }
}

// ---------------- LoRA T = Xn @ A^T  (bf16 Xn [M,K], fp32 A [16,K]) ----------------
// writes T2 [M,32] bf16, cols 16..31 zero (K-extension trick for the GEMM)
__global__ __launch_bounds__(256) void k_lora_t(const short* __restrict__ Xn,
                                                const float* __restrict__ A,
                                                short* __restrict__ T2, int K) {
  int m = blockIdx.x;
  int g = threadIdx.x & 15;   // k phase
  int r = threadIdx.x >> 4;   // rank index
  const short* xr = Xn + (long)m * K;
  const float* ar = A + (long)r * K;
  float p = 0.f;
  for (int k = g; k < K; k += 16) p += b2f((unsigned short)xr[k]) * ar[k];
  __shared__ float red[256];
  red[threadIdx.x] = p;
  __syncthreads();
  if (threadIdx.x < 32) {
    float s = 0.f;
    if (threadIdx.x < 16) {
      int rr = threadIdx.x;
#pragma unroll
      for (int gg = 0; gg < 16; ++gg) s += red[rr * 16 + gg];
    }
    T2[(long)m * 32 + threadIdx.x] = (threadIdx.x < 16) ? f2b(s) : (short)0;
  }
}

// ---------------- Bm [N,16] fp32 -> Bm2 [N,32] bf16 zero-padded ----------------
__global__ void k_prep_bm2(const float* __restrict__ Bm, short* __restrict__ Bm2, int N) {
  int i = blockIdx.x * 256 + threadIdx.x;
  if (i >= N * 32) return;
  int c = i & 31, n = i >> 5;
  Bm2[i] = (c < 16) ? f2b(Bm[(long)n * 16 + c]) : (short)0;
}

// ---------------- QKV GEMM: C = Xn @ W^T + bias + lora, then RoPE + transpose ----
// N = K = 2048 fixed. Each wave: 32 rows x 128 cols, so each lane holds a full
// head-dim row segment (d and d^64 both in-register) -> RoPE without LDS.
// Output written transposed to [B, NH, S, HD] bf16.
__global__ __launch_bounds__(256) void k_gemm_qkv(
    const short* __restrict__ A, const short* __restrict__ W,
    const float* __restrict__ bias,
    const short* __restrict__ T2, const short* __restrict__ Bm2,
    const float* __restrict__ cs, const float* __restrict__ sn,
    short* __restrict__ out, int do_rope) {
  const int K = H_;
  int lane = threadIdx.x & 63, wave = threadIdx.x >> 6;
  int row0 = blockIdx.y * 128 + wave * 32;
  int col0 = blockIdx.x * 128;
  int lr = lane & 15, lk = (lane >> 4) << 3;
  const short* Ap = A + (long)(row0 + lr) * K + lk;
  const short* Wp = W + (long)(col0 + lr) * K + lk;
  f32x4 acc[2][8] = {};
  for (int k0 = 0; k0 < K; k0 += 32) {
    bf16x8 a[2], b[8];
#pragma unroll
    for (int i = 0; i < 2; ++i) a[i] = *(const bf16x8*)(Ap + (long)i * 16 * K + k0);
#pragma unroll
    for (int j = 0; j < 8; ++j) b[j] = *(const bf16x8*)(Wp + (long)j * 16 * K + k0);
#pragma unroll
    for (int i = 0; i < 2; ++i)
#pragma unroll
      for (int j = 0; j < 8; ++j)
        acc[i][j] = __builtin_amdgcn_mfma_f32_16x16x32_bf16(a[i], b[j], acc[i][j], 0, 0, 0);
  }
  { // LoRA K-extension
    bf16x8 a[2], b[8];
#pragma unroll
    for (int i = 0; i < 2; ++i) a[i] = *(const bf16x8*)(T2 + (long)(row0 + i * 16 + lr) * 32 + lk);
#pragma unroll
    for (int j = 0; j < 8; ++j) b[j] = *(const bf16x8*)(Bm2 + (long)(col0 + j * 16 + lr) * 32 + lk);
#pragma unroll
    for (int i = 0; i < 2; ++i)
#pragma unroll
      for (int j = 0; j < 8; ++j)
        acc[i][j] = __builtin_amdgcn_mfma_f32_16x16x32_bf16(a[i], b[j], acc[i][j], 0, 0, 0);
  }
  int rquad = (lane >> 4) * 4;
  int head = blockIdx.x;
#pragma unroll
  for (int i = 0; i < 2; ++i) {
#pragma unroll
    for (int t = 0; t < 4; ++t) {
      int row = row0 + i * 16 + rquad + t;
      int bb = row >> 11, sr = row & (S_ - 1);
      float vals[8];
#pragma unroll
      for (int j = 0; j < 8; ++j) vals[j] = acc[i][j][t] + bias[col0 + j * 16 + lr];
      long obase = ((long)(bb * NH_ + head) * S_ + sr) * HD_;
      if (do_rope) {
#pragma unroll
        for (int j = 0; j < 8; ++j) {
          int d = j * 16 + lr;
          float rot = (j < 4) ? -vals[j + 4] : vals[j - 4];
          out[obase + d] = f2b(vals[j] * cs[sr * HD_ + d] + rot * sn[sr * HD_ + d]);
        }
      } else {
#pragma unroll
        for (int j = 0; j < 8; ++j) out[obase + j * 16 + lr] = f2b(vals[j]);
      }
    }
  }
}

// ---------------- General GEMM: C[M,N] = A[M,K] @ W[N,K]^T + bias + T2@Bm2^T ------
// epilogue: silu (apply silu to own result), gatebf (multiply by bf16 buffer,
// may alias outb -> NOT restrict), resid (fp32 add), outf/outb output.
__global__ __launch_bounds__(256) void k_gemm(
    const short* __restrict__ A, const short* __restrict__ W,
    const float* __restrict__ bias,
    const short* __restrict__ T2, const short* __restrict__ Bm2,
    const float* __restrict__ resid, const short* gatebf, int do_silu,
    float* __restrict__ outf, short* outb,
    int N, int K) {
  int lane = threadIdx.x & 63, wave = threadIdx.x >> 6;
  int wm = wave >> 1, wn = wave & 1;
  int row0 = blockIdx.y * 128 + wm * 64;
  int col0 = blockIdx.x * 128 + wn * 64;
  int lr = lane & 15;
  int lk = (lane >> 4) << 3;
  const short* Ap = A + (long)(row0 + lr) * K + lk;
  const short* Wp = W + (long)(col0 + lr) * K + lk;
  f32x4 acc[4][4] = {};
  for (int k0 = 0; k0 < K; k0 += 32) {
    bf16x8 a[4], b[4];
#pragma unroll
    for (int i = 0; i < 4; ++i) a[i] = *(const bf16x8*)(Ap + (long)i * 16 * K + k0);
#pragma unroll
    for (int j = 0; j < 4; ++j) b[j] = *(const bf16x8*)(Wp + (long)j * 16 * K + k0);
#pragma unroll
    for (int i = 0; i < 4; ++i)
#pragma unroll
      for (int j = 0; j < 4; ++j)
        acc[i][j] = __builtin_amdgcn_mfma_f32_16x16x32_bf16(a[i], b[j], acc[i][j], 0, 0, 0);
  }
  { // LoRA K-extension
    bf16x8 a[4], b[4];
#pragma unroll
    for (int i = 0; i < 4; ++i) a[i] = *(const bf16x8*)(T2 + (long)(row0 + i * 16 + lr) * 32 + lk);
#pragma unroll
    for (int j = 0; j < 4; ++j) b[j] = *(const bf16x8*)(Bm2 + (long)(col0 + j * 16 + lr) * 32 + lk);
#pragma unroll
    for (int i = 0; i < 4; ++i)
#pragma unroll
      for (int j = 0; j < 4; ++j)
        acc[i][j] = __builtin_amdgcn_mfma_f32_16x16x32_bf16(a[i], b[j], acc[i][j], 0, 0, 0);
  }
  int rquad = (lane >> 4) * 4;
#pragma unroll
  for (int i = 0; i < 4; ++i) {
#pragma unroll
    for (int j = 0; j < 4; ++j) {
      int col = col0 + j * 16 + lr;
      float bc = bias[col];
#pragma unroll
      for (int t = 0; t < 4; ++t) {
        int row = row0 + i * 16 + rquad + t;
        long idx = (long)row * N + col;
        float v2 = acc[i][j][t] + bc;
        if (do_silu) v2 = v2 / (1.f + __expf(-v2));
        if (gatebf) v2 *= b2f((unsigned short)gatebf[idx]);
        if (resid) v2 += resid[idx];
        if (outf) outf[idx] = v2;
        else outb[idx] = f2b(v2);
      }
    }
  }
}

// ---------------- Flash attention (causal) ----------------
// block: 256 thr = 4 waves; 16 q-rows per block (4 per wave); lane <-> key
__global__ __launch_bounds__(256) void k_attn(const short* __restrict__ Q,
                                              const short* __restrict__ Kt,
                                              const short* __restrict__ V,
                                              short* __restrict__ att) {
  __shared__ float k_lds[64 * 128];      // fp32, xor-swizzled float4 chunks
  __shared__ unsigned v_lds[64 * 64];    // raw bf16 pairs
  __shared__ float q_lds[16 * 128];      // fp32, pre-scaled
  __shared__ float p_lds[4][64][4];      // [wave][key][r]
  int lane = threadIdx.x & 63, wave = threadIdx.x >> 6;
  int blk = blockIdx.x;
  int qt = blk & (S_ / 16 - 1);
  int bh = blk >> 7;
  int q0 = qt * 16;
  long base = (long)bh * S_ * HD_;
  const float scale = 0.08838834764831845f;  // 1/sqrt(128)
  for (int idx = threadIdx.x; idx < 16 * 128; idx += 256) {
    int r = idx >> 7, d = idx & 127;
    q_lds[idx] = b2f((unsigned short)Q[base + (long)(q0 + r) * HD_ + d]) * scale;
  }
  float m_r[4], l_r[4], o0[4], o1[4];
#pragma unroll
  for (int r = 0; r < 4; ++r) { m_r[r] = -3.0e38f; l_r[r] = 0.f; o0[r] = 0.f; o1[r] = 0.f; }
  int kbmax = (q0 + 15) >> 6;
  for (int kb = 0; kb <= kbmax; ++kb) {
    int kk0 = kb * 64;
    __syncthreads();
    for (int idx = threadIdx.x; idx < 64 * 32; idx += 256) {
      int rowk = idx >> 5, c = idx & 31;
      const short* src = Kt + base + (long)(kk0 + rowk) * HD_ + c * 4;
      float4 f4;
      f4.x = b2f((unsigned short)src[0]); f4.y = b2f((unsigned short)src[1]);
      f4.z = b2f((unsigned short)src[2]); f4.w = b2f((unsigned short)src[3]);
      int pc = c ^ (rowk & 31);
      *(float4*)&k_lds[rowk * 128 + pc * 4] = f4;
    }
    {
      const uint4* vsrc = (const uint4*)(V + base + (long)kk0 * HD_);
      uint4* vdst = (uint4*)v_lds;
      for (int idx = threadIdx.x; idx < 64 * 128 / 8; idx += 256) vdst[idx] = vsrc[idx];
    }
    __syncthreads();
    float sc[4] = {0.f, 0.f, 0.f, 0.f};
#pragma unroll
    for (int c = 0; c < 32; ++c) {
      float4 k4 = *(const float4*)&k_lds[lane * 128 + ((c ^ (lane & 31)) << 2)];
#pragma unroll
      for (int r = 0; r < 4; ++r) {
        float4 q4 = *(const float4*)&q_lds[(wave * 4 + r) * 128 + (c << 2)];
        sc[r] += q4.x * k4.x + q4.y * k4.y + q4.z * k4.z + q4.w * k4.w;
      }
    }
    int key = kk0 + lane;
#pragma unroll
    for (int r = 0; r < 4; ++r) {
      int qrow = q0 + wave * 4 + r;
      float sv = (key <= qrow) ? sc[r] : -1e30f;
      float mx = sv;
#pragma unroll
      for (int o = 32; o; o >>= 1) mx = fmaxf(mx, __shfl_xor(mx, o));
      float mnew = fmaxf(m_r[r], mx);
      float alpha = __expf(m_r[r] - mnew);
      float p = __expf(sv - mnew);
      float ps = p;
#pragma unroll
      for (int o = 32; o; o >>= 1) ps += __shfl_xor(ps, o);
      l_r[r] = l_r[r] * alpha + ps;
      m_r[r] = mnew;
      o0[r] *= alpha; o1[r] *= alpha;
      p_lds[wave][lane][r] = p;   // per-wave region, same-wave in-order DS ops
    }
#pragma unroll 8
    for (int j2 = 0; j2 < 64; ++j2) {
      float4 p4 = *(const float4*)&p_lds[wave][j2][0];
      unsigned vrw = v_lds[j2 * 64 + lane];
      float v0 = b2f((unsigned short)(vrw & 0xffffu));
      float v1 = b2f((unsigned short)(vrw >> 16));
      o0[0] += p4.x * v0; o1[0] += p4.x * v1;
      o0[1] += p4.y * v0; o1[1] += p4.y * v1;
      o0[2] += p4.z * v0; o1[2] += p4.z * v1;
      o0[3] += p4.w * v0; o1[3] += p4.w * v1;
    }
  }
  int h = bh & (NH_ - 1), b = bh >> 4;
#pragma unroll
  for (int r = 0; r < 4; ++r) {
    int qrow = q0 + wave * 4 + r;
    float inv = 1.f / l_r[r];
    long o = ((long)(b * S_ + qrow)) * H_ + h * HD_ + lane * 2;
    unsigned lo = (unsigned short)f2b(o0[r] * inv);
    unsigned hi = (unsigned short)f2b(o1[r] * inv);
    *(unsigned*)(att + o) = lo | (hi << 16);
  }
}

// ---------------- host ----------------
extern "C" void kernel_launch(void* const* d_in, const int* in_sizes, int n_in,
                              void* d_out, int out_size, void* d_ws, size_t ws_size,
                              hipStream_t stream) {
  const float* x    = (const float*)d_in[0];
  const float* nw1  = (const float*)d_in[1];
  const float* nw2  = (const float*)d_in[2];
  const float* cosb = (const float*)d_in[3];
  const float* sinb = (const float*)d_in[4];
  const float *W[7], *Bias[7], *La[7], *Lb[7];
  for (int p = 0; p < 7; ++p) {
    W[p]    = (const float*)d_in[5 + p * 4];
    Bias[p] = (const float*)d_in[6 + p * 4];
    La[p]   = (const float*)d_in[7 + p * 4];
    Lb[p]   = (const float*)d_in[8 + p * 4];
  }
  const int wsz[7] = {H_*H_, H_*H_, H_*H_, H_*H_, INTER_*H_, INTER_*H_, INTER_*H_};

  // workspace arena: 135,356,416 bytes total
  char* ws = (char*)d_ws;
  size_t off = 0;
  short* wbuf = (short*)(ws + off); off += (size_t)INTER_ * H_ * 2;      // 22.5 MB shared weight buf
  short* T2   = (short*)(ws + off); off += (size_t)M_ * 32 * 2;
  short* Bm2  = (short*)(ws + off); off += (size_t)INTER_ * 32 * 2;
  short* xn   = (short*)(ws + off); off += (size_t)M_ * H_ * 2;          // xn1 -> attb -> xn2
  char*  regC = ws + off;           off += (size_t)M_ * H_ * 2 * 3;      // qr/kr/vr -> xmed
  short* gact = (short*)(ws + off); off += (size_t)M_ * INTER_ * 2;      // silu(gate) -> h (in place)
  short* qr = (short*)regC;
  short* kr = (short*)(regC + (size_t)M_ * H_ * 2);
  short* vr = (short*)(regC + (size_t)M_ * H_ * 2 * 2);
  float* xmed = (float*)regC;
  short* attb = xn;
  float* outp = (float*)d_out;

  auto conv = [&](int p) {
    k_f2b<<<dim3((wsz[p] + 255) / 256), dim3(256), 0, stream>>>(W[p], wbuf, wsz[p]);
  };
  auto lora = [&](int p, const short* Ain, int K, int N) {
    k_lora_t<<<dim3(M_), dim3(256), 0, stream>>>(Ain, La[p], T2, K);
    k_prep_bm2<<<dim3((N * 32 + 255) / 256), dim3(256), 0, stream>>>(Lb[p], Bm2, N);
  };

  // 1. RMSNorm 1
  k_rmsnorm<<<dim3(M_), dim3(256), 0, stream>>>(x, nw1, xn);
  // 2. Q,K,V projections fused with RoPE + transpose -> [B,NH,S,HD]
  conv(0); lora(0, xn, H_, H_);
  k_gemm_qkv<<<dim3(NH_, M_ / 128), dim3(256), 0, stream>>>(xn, wbuf, Bias[0], T2, Bm2, cosb, sinb, qr, 1);
  conv(1); lora(1, xn, H_, H_);
  k_gemm_qkv<<<dim3(NH_, M_ / 128), dim3(256), 0, stream>>>(xn, wbuf, Bias[1], T2, Bm2, cosb, sinb, kr, 1);
  conv(2); lora(2, xn, H_, H_);
  k_gemm_qkv<<<dim3(NH_, M_ / 128), dim3(256), 0, stream>>>(xn, wbuf, Bias[2], T2, Bm2, cosb, sinb, vr, 0);
  // 3. attention -> attb [B,S,H] bf16 (aliases xn; xn1 dead)
  k_attn<<<dim3(B_ * NH_ * (S_ / 16)), dim3(256), 0, stream>>>(qr, kr, vr, attb);
  // 4. O projection + residual(x) -> xmed fp32 (aliases qr region; qkv dead)
  conv(3); lora(3, attb, H_, H_);
  k_gemm<<<dim3(H_ / 128, M_ / 128), dim3(256), 0, stream>>>(
      attb, wbuf, Bias[3], T2, Bm2, x, nullptr, 0, xmed, nullptr, H_, H_);
  // 5. RMSNorm 2 -> xn (attb dead)
  k_rmsnorm<<<dim3(M_), dim3(256), 0, stream>>>(xmed, nw2, xn);
  // 6. gate -> silu(gate) bf16
  conv(4); lora(4, xn, H_, INTER_);
  k_gemm<<<dim3(INTER_ / 128, M_ / 128), dim3(256), 0, stream>>>(
      xn, wbuf, Bias[4], T2, Bm2, nullptr, nullptr, 1, nullptr, gact, INTER_, H_);
  // 7. up * silu(gate) -> gact in place (same thread reads then writes same idx)
  conv(5); lora(5, xn, H_, INTER_);
  k_gemm<<<dim3(INTER_ / 128, M_ / 128), dim3(256), 0, stream>>>(
      xn, wbuf, Bias[5], T2, Bm2, nullptr, gact, 0, nullptr, gact, INTER_, H_);
  // 8. down + residual(xmed) -> d_out fp32
  conv(6); lora(6, gact, INTER_, H_);
  k_gemm<<<dim3(H_ / 128, M_ / 128), dim3(256), 0, stream>>>(
      gact, wbuf, Bias[6], T2, Bm2, xmed, nullptr, 0, outp, nullptr, H_, INTER_);
}

// Round 3
// 2996.717 us; speedup vs baseline: 1.3097x; 1.3097x over previous
//
#include <hip/hip_runtime.h>
#include <hip/hip_bf16.h>

// Fused Llama layer: B=2 S=2048 H=2048 NH=16 HD=128 INTER=5504 R=16
#define B_ 2
#define S_ 2048
#define H_ 2048
#define NH_ 16
#define HD_ 128
#define INTER_ 5504
#define M_ (B_*S_)

using bf16x8 = __attribute__((ext_vector_type(8))) short;
using f32x4  = __attribute__((ext_vector_type(4))) float;

__device__ __forceinline__ float b2f(unsigned short u) {
  union { unsigned u; float f; } c; c.u = ((unsigned)u) << 16; return c.f;
}
__device__ __forceinline__ short f2b(float f) {
  union { float f; unsigned u; } c; c.f = f;
  unsigned r = (c.u + 0x7fffu + ((c.u >> 16) & 1u)) >> 16;
  return (short)r;
}

typedef const __attribute__((address_space(1))) void* gvp;
typedef __attribute__((address_space(3))) void* lvp;
__device__ __forceinline__ void gl2lds16(const short* g, short* l) {
  __builtin_amdgcn_global_load_lds((gvp)g, (lvp)l, 16, 0, 0);
}

// ---------------- fp32 -> bf16 weight convert ----------------
__global__ void k_f2b(const float* __restrict__ in, short* __restrict__ out, int n) {
  int i = blockIdx.x * 256 + threadIdx.x;
  if (i < n) out[i] = f2b(in[i]);
}

// ---------------- RMSNorm (fp32 in, bf16 out) ----------------
__global__ __launch_bounds__(256) void k_rmsnorm(const float* __restrict__ x,
                                                 const float* __restrict__ w,
                                                 short* __restrict__ out) {
  int row = blockIdx.x;
  const float4* xr = (const float4*)(x + (long)row * H_);
  float ss = 0.f;
  float4 v[2];
#pragma unroll
  for (int it = 0; it < 2; ++it) {
    float4 t = xr[threadIdx.x + it * 256];
    v[it] = t;
    ss += t.x*t.x + t.y*t.y + t.z*t.z + t.w*t.w;
  }
#pragma unroll
  for (int o = 32; o; o >>= 1) ss += __shfl_xor(ss, o);
  __shared__ float s4[4];
  if ((threadIdx.x & 63) == 0) s4[threadIdx.x >> 6] = ss;
  __syncthreads();
  float r = rsqrtf((s4[0] + s4[1] + s4[2] + s4[3]) * (1.f / H_) + 1e-5f);
  const float4* wr = (const float4*)w;
  short4* orow = (short4*)(out + (long)row * H_);
#pragma unroll
  for (int it = 0; it < 2; ++it) {
    float4 t = v[it];
    float4 ww = wr[threadIdx.x + it * 256];
    short4 o4;
    o4.x = f2b(t.x * r * ww.x); o4.y = f2b(t.y * r * ww.y);
    o4.z = f2b(t.z * r * ww.z); o4.w = f2b(t.w * r * ww.w);
    orow[threadIdx.x + it * 256] = o4;
  }
}

// ---------------- LoRA T = Xn @ A^T  (bf16 Xn [M,K], fp32 A [16,K]) ----------------
__global__ __launch_bounds__(256) void k_lora_t(const short* __restrict__ Xn,
                                                const float* __restrict__ A,
                                                short* __restrict__ T2, int K) {
  int m = blockIdx.x;
  int g = threadIdx.x & 15;
  int r = threadIdx.x >> 4;
  const short* xr = Xn + (long)m * K;
  const float* ar = A + (long)r * K;
  float p = 0.f;
  for (int k = g; k < K; k += 16) p += b2f((unsigned short)xr[k]) * ar[k];
  __shared__ float red[256];
  red[threadIdx.x] = p;
  __syncthreads();
  if (threadIdx.x < 32) {
    float s = 0.f;
    if (threadIdx.x < 16) {
      int rr = threadIdx.x;
#pragma unroll
      for (int gg = 0; gg < 16; ++gg) s += red[rr * 16 + gg];
    }
    T2[(long)m * 32 + threadIdx.x] = (threadIdx.x < 16) ? f2b(s) : (short)0;
  }
}

// ---------------- Bm [N,16] fp32 -> Bm2 [N,32] bf16 zero-padded ----------------
__global__ void k_prep_bm2(const float* __restrict__ Bm, short* __restrict__ Bm2, int N) {
  int i = blockIdx.x * 256 + threadIdx.x;
  if (i >= N * 32) return;
  int c = i & 31, n = i >> 5;
  Bm2[i] = (c < 16) ? f2b(Bm[(long)n * 16 + c]) : (short)0;
}

// ---------------- QKV GEMM (LDS-staged) + RoPE + transpose ----------------
// wave tile: 32 rows x 128 cols (full head in-lane for RoPE). N=K=2048.
__global__ __launch_bounds__(256) void k_gemm_qkv(
    const short* __restrict__ A, const short* __restrict__ W,
    const float* __restrict__ bias,
    const short* __restrict__ T2, const short* __restrict__ Bm2,
    const float* __restrict__ cs, const float* __restrict__ sn,
    short* __restrict__ out, int do_rope) {
  const int K = H_;
  __shared__ short As[128 * 32];
  __shared__ short Bs[128 * 32];
  int t = threadIdx.x;
  int lane = t & 63, wave = t >> 6;
  int row0 = blockIdx.y * 128;
  int col0 = blockIdx.x * 128;
  int lr = lane & 15, lk = (lane >> 4) << 3;
  int srow = t >> 2, skc = t & 3;          // staging: row 0..63, kchunk 0..3
  const short* Ag0 = A + (long)(row0 + srow) * K + skc * 8;
  const short* Ag1 = A + (long)(row0 + 64 + srow) * K + skc * 8;
  const short* Wg0 = W + (long)(col0 + srow) * K + skc * 8;
  const short* Wg1 = W + (long)(col0 + 64 + srow) * K + skc * 8;
  short* Al0 = As + wave * 512;            // bytes: wave*1024
  short* Al1 = As + 2048 + wave * 512;
  short* Bl0 = Bs + wave * 512;
  short* Bl1 = Bs + 2048 + wave * 512;
  f32x4 acc[2][8] = {};
  for (int k0 = 0; k0 < K; k0 += 32) {
    gl2lds16(Ag0 + k0, Al0);
    gl2lds16(Ag1 + k0, Al1);
    gl2lds16(Wg0 + k0, Bl0);
    gl2lds16(Wg1 + k0, Bl1);
    __syncthreads();
    bf16x8 a[2], b[8];
#pragma unroll
    for (int i = 0; i < 2; ++i) a[i] = *(const bf16x8*)(As + (wave * 32 + i * 16 + lr) * 32 + lk);
#pragma unroll
    for (int j = 0; j < 8; ++j) b[j] = *(const bf16x8*)(Bs + (j * 16 + lr) * 32 + lk);
#pragma unroll
    for (int i = 0; i < 2; ++i)
#pragma unroll
      for (int j = 0; j < 8; ++j)
        acc[i][j] = __builtin_amdgcn_mfma_f32_16x16x32_bf16(a[i], b[j], acc[i][j], 0, 0, 0);
    __syncthreads();
  }
  { // LoRA K-extension (direct from global)
    bf16x8 a[2], b[8];
#pragma unroll
    for (int i = 0; i < 2; ++i) a[i] = *(const bf16x8*)(T2 + (long)(row0 + wave * 32 + i * 16 + lr) * 32 + lk);
#pragma unroll
    for (int j = 0; j < 8; ++j) b[j] = *(const bf16x8*)(Bm2 + (long)(col0 + j * 16 + lr) * 32 + lk);
#pragma unroll
    for (int i = 0; i < 2; ++i)
#pragma unroll
      for (int j = 0; j < 8; ++j)
        acc[i][j] = __builtin_amdgcn_mfma_f32_16x16x32_bf16(a[i], b[j], acc[i][j], 0, 0, 0);
  }
  int rquad = (lane >> 4) * 4;
  int head = blockIdx.x;
#pragma unroll
  for (int i = 0; i < 2; ++i) {
#pragma unroll
    for (int tt = 0; tt < 4; ++tt) {
      int row = row0 + wave * 32 + i * 16 + rquad + tt;
      int bb = row >> 11, sr = row & (S_ - 1);
      float vals[8];
#pragma unroll
      for (int j = 0; j < 8; ++j) vals[j] = acc[i][j][tt] + bias[col0 + j * 16 + lr];
      long obase = ((long)(bb * NH_ + head) * S_ + sr) * HD_;
      if (do_rope) {
#pragma unroll
        for (int j = 0; j < 8; ++j) {
          int d = j * 16 + lr;
          float rot = (j < 4) ? -vals[j + 4] : vals[j - 4];
          out[obase + d] = f2b(vals[j] * cs[sr * HD_ + d] + rot * sn[sr * HD_ + d]);
        }
      } else {
#pragma unroll
        for (int j = 0; j < 8; ++j) out[obase + j * 16 + lr] = f2b(vals[j]);
      }
    }
  }
}

// ---------------- General GEMM (LDS-staged): C = A@W^T + bias + lora ----------------
__global__ __launch_bounds__(256) void k_gemm(
    const short* __restrict__ A, const short* __restrict__ W,
    const float* __restrict__ bias,
    const short* __restrict__ T2, const short* __restrict__ Bm2,
    const float* __restrict__ resid, const short* gatebf, int do_silu,
    float* __restrict__ outf, short* outb,
    int N, int K) {
  __shared__ short As[128 * 32];
  __shared__ short Bs[128 * 32];
  int t = threadIdx.x;
  int lane = t & 63, wave = t >> 6;
  int wm = wave >> 1, wn = wave & 1;
  int row0 = blockIdx.y * 128;
  int col0 = blockIdx.x * 128;
  int lr = lane & 15, lk = (lane >> 4) << 3;
  int srow = t >> 2, skc = t & 3;
  const short* Ag0 = A + (long)(row0 + srow) * K + skc * 8;
  const short* Ag1 = A + (long)(row0 + 64 + srow) * K + skc * 8;
  const short* Wg0 = W + (long)(col0 + srow) * K + skc * 8;
  const short* Wg1 = W + (long)(col0 + 64 + srow) * K + skc * 8;
  short* Al0 = As + wave * 512;
  short* Al1 = As + 2048 + wave * 512;
  short* Bl0 = Bs + wave * 512;
  short* Bl1 = Bs + 2048 + wave * 512;
  f32x4 acc[4][4] = {};
  for (int k0 = 0; k0 < K; k0 += 32) {
    gl2lds16(Ag0 + k0, Al0);
    gl2lds16(Ag1 + k0, Al1);
    gl2lds16(Wg0 + k0, Bl0);
    gl2lds16(Wg1 + k0, Bl1);
    __syncthreads();
    bf16x8 a[4], b[4];
#pragma unroll
    for (int i = 0; i < 4; ++i) a[i] = *(const bf16x8*)(As + (wm * 64 + i * 16 + lr) * 32 + lk);
#pragma unroll
    for (int j = 0; j < 4; ++j) b[j] = *(const bf16x8*)(Bs + (wn * 64 + j * 16 + lr) * 32 + lk);
#pragma unroll
    for (int i = 0; i < 4; ++i)
#pragma unroll
      for (int j = 0; j < 4; ++j)
        acc[i][j] = __builtin_amdgcn_mfma_f32_16x16x32_bf16(a[i], b[j], acc[i][j], 0, 0, 0);
    __syncthreads();
  }
  { // LoRA K-extension
    bf16x8 a[4], b[4];
#pragma unroll
    for (int i = 0; i < 4; ++i) a[i] = *(const bf16x8*)(T2 + (long)(row0 + wm * 64 + i * 16 + lr) * 32 + lk);
#pragma unroll
    for (int j = 0; j < 4; ++j) b[j] = *(const bf16x8*)(Bm2 + (long)(col0 + wn * 64 + j * 16 + lr) * 32 + lk);
#pragma unroll
    for (int i = 0; i < 4; ++i)
#pragma unroll
      for (int j = 0; j < 4; ++j)
        acc[i][j] = __builtin_amdgcn_mfma_f32_16x16x32_bf16(a[i], b[j], acc[i][j], 0, 0, 0);
  }
  int rquad = (lane >> 4) * 4;
#pragma unroll
  for (int i = 0; i < 4; ++i) {
#pragma unroll
    for (int j = 0; j < 4; ++j) {
      int col = col0 + wn * 64 + j * 16 + lr;
      float bc = bias[col];
#pragma unroll
      for (int tt = 0; tt < 4; ++tt) {
        int row = row0 + wm * 64 + i * 16 + rquad + tt;
        long idx = (long)row * N + col;
        float v2 = acc[i][j][tt] + bc;
        if (do_silu) v2 = v2 / (1.f + __expf(-v2));
        if (gatebf) v2 *= b2f((unsigned short)gatebf[idx]);
        if (resid) v2 += resid[idx];
        if (outf) outf[idx] = v2;
        else outb[idx] = f2b(v2);
      }
    }
  }
}

// ---------------- Flash attention (causal) — unchanged this round ----------------
__global__ __launch_bounds__(256) void k_attn(const short* __restrict__ Q,
                                              const short* __restrict__ Kt,
                                              const short* __restrict__ V,
                                              short* __restrict__ att) {
  __shared__ float k_lds[64 * 128];
  __shared__ unsigned v_lds[64 * 64];
  __shared__ float q_lds[16 * 128];
  __shared__ float p_lds[4][64][4];
  int lane = threadIdx.x & 63, wave = threadIdx.x >> 6;
  int blk = blockIdx.x;
  int qt = blk & (S_ / 16 - 1);
  int bh = blk >> 7;
  int q0 = qt * 16;
  long base = (long)bh * S_ * HD_;
  const float scale = 0.08838834764831845f;
  for (int idx = threadIdx.x; idx < 16 * 128; idx += 256) {
    int r = idx >> 7, d = idx & 127;
    q_lds[idx] = b2f((unsigned short)Q[base + (long)(q0 + r) * HD_ + d]) * scale;
  }
  float m_r[4], l_r[4], o0[4], o1[4];
#pragma unroll
  for (int r = 0; r < 4; ++r) { m_r[r] = -3.0e38f; l_r[r] = 0.f; o0[r] = 0.f; o1[r] = 0.f; }
  int kbmax = (q0 + 15) >> 6;
  for (int kb = 0; kb <= kbmax; ++kb) {
    int kk0 = kb * 64;
    __syncthreads();
    for (int idx = threadIdx.x; idx < 64 * 32; idx += 256) {
      int rowk = idx >> 5, c = idx & 31;
      const short* src = Kt + base + (long)(kk0 + rowk) * HD_ + c * 4;
      float4 f4;
      f4.x = b2f((unsigned short)src[0]); f4.y = b2f((unsigned short)src[1]);
      f4.z = b2f((unsigned short)src[2]); f4.w = b2f((unsigned short)src[3]);
      int pc = c ^ (rowk & 31);
      *(float4*)&k_lds[rowk * 128 + pc * 4] = f4;
    }
    {
      const uint4* vsrc = (const uint4*)(V + base + (long)kk0 * HD_);
      uint4* vdst = (uint4*)v_lds;
      for (int idx = threadIdx.x; idx < 64 * 128 / 8; idx += 256) vdst[idx] = vsrc[idx];
    }
    __syncthreads();
    float sc[4] = {0.f, 0.f, 0.f, 0.f};
#pragma unroll
    for (int c = 0; c < 32; ++c) {
      float4 k4 = *(const float4*)&k_lds[lane * 128 + ((c ^ (lane & 31)) << 2)];
#pragma unroll
      for (int r = 0; r < 4; ++r) {
        float4 q4 = *(const float4*)&q_lds[(wave * 4 + r) * 128 + (c << 2)];
        sc[r] += q4.x * k4.x + q4.y * k4.y + q4.z * k4.z + q4.w * k4.w;
      }
    }
    int key = kk0 + lane;
#pragma unroll
    for (int r = 0; r < 4; ++r) {
      int qrow = q0 + wave * 4 + r;
      float sv = (key <= qrow) ? sc[r] : -1e30f;
      float mx = sv;
#pragma unroll
      for (int o = 32; o; o >>= 1) mx = fmaxf(mx, __shfl_xor(mx, o));
      float mnew = fmaxf(m_r[r], mx);
      float alpha = __expf(m_r[r] - mnew);
      float p = __expf(sv - mnew);
      float ps = p;
#pragma unroll
      for (int o = 32; o; o >>= 1) ps += __shfl_xor(ps, o);
      l_r[r] = l_r[r] * alpha + ps;
      m_r[r] = mnew;
      o0[r] *= alpha; o1[r] *= alpha;
      p_lds[wave][lane][r] = p;
    }
#pragma unroll 8
    for (int j2 = 0; j2 < 64; ++j2) {
      float4 p4 = *(const float4*)&p_lds[wave][j2][0];
      unsigned vrw = v_lds[j2 * 64 + lane];
      float v0 = b2f((unsigned short)(vrw & 0xffffu));
      float v1 = b2f((unsigned short)(vrw >> 16));
      o0[0] += p4.x * v0; o1[0] += p4.x * v1;
      o0[1] += p4.y * v0; o1[1] += p4.y * v1;
      o0[2] += p4.z * v0; o1[2] += p4.z * v1;
      o0[3] += p4.w * v0; o1[3] += p4.w * v1;
    }
  }
  int h = bh & (NH_ - 1), b = bh >> 4;
#pragma unroll
  for (int r = 0; r < 4; ++r) {
    int qrow = q0 + wave * 4 + r;
    float inv = 1.f / l_r[r];
    long o = ((long)(b * S_ + qrow)) * H_ + h * HD_ + lane * 2;
    unsigned lo = (unsigned short)f2b(o0[r] * inv);
    unsigned hi = (unsigned short)f2b(o1[r] * inv);
    *(unsigned*)(att + o) = lo | (hi << 16);
  }
}

// ---------------- host ----------------
extern "C" void kernel_launch(void* const* d_in, const int* in_sizes, int n_in,
                              void* d_out, int out_size, void* d_ws, size_t ws_size,
                              hipStream_t stream) {
  const float* x    = (const float*)d_in[0];
  const float* nw1  = (const float*)d_in[1];
  const float* nw2  = (const float*)d_in[2];
  const float* cosb = (const float*)d_in[3];
  const float* sinb = (const float*)d_in[4];
  const float *W[7], *Bias[7], *La[7], *Lb[7];
  for (int p = 0; p < 7; ++p) {
    W[p]    = (const float*)d_in[5 + p * 4];
    Bias[p] = (const float*)d_in[6 + p * 4];
    La[p]   = (const float*)d_in[7 + p * 4];
    Lb[p]   = (const float*)d_in[8 + p * 4];
  }
  const int wsz[7] = {H_*H_, H_*H_, H_*H_, H_*H_, INTER_*H_, INTER_*H_, INTER_*H_};

  char* ws = (char*)d_ws;
  size_t off = 0;
  short* wbuf = (short*)(ws + off); off += (size_t)INTER_ * H_ * 2;
  short* T2   = (short*)(ws + off); off += (size_t)M_ * 32 * 2;
  short* Bm2  = (short*)(ws + off); off += (size_t)INTER_ * 32 * 2;
  short* xn   = (short*)(ws + off); off += (size_t)M_ * H_ * 2;
  char*  regC = ws + off;           off += (size_t)M_ * H_ * 2 * 3;
  short* gact = (short*)(ws + off); off += (size_t)M_ * INTER_ * 2;
  short* qr = (short*)regC;
  short* kr = (short*)(regC + (size_t)M_ * H_ * 2);
  short* vr = (short*)(regC + (size_t)M_ * H_ * 2 * 2);
  float* xmed = (float*)regC;
  short* attb = xn;
  float* outp = (float*)d_out;

  auto conv = [&](int p) {
    k_f2b<<<dim3((wsz[p] + 255) / 256), dim3(256), 0, stream>>>(W[p], wbuf, wsz[p]);
  };
  auto lora = [&](int p, const short* Ain, int K, int N) {
    k_lora_t<<<dim3(M_), dim3(256), 0, stream>>>(Ain, La[p], T2, K);
    k_prep_bm2<<<dim3((N * 32 + 255) / 256), dim3(256), 0, stream>>>(Lb[p], Bm2, N);
  };

  // 1. RMSNorm 1
  k_rmsnorm<<<dim3(M_), dim3(256), 0, stream>>>(x, nw1, xn);
  // 2. Q,K,V projections fused with RoPE + transpose -> [B,NH,S,HD]
  conv(0); lora(0, xn, H_, H_);
  k_gemm_qkv<<<dim3(NH_, M_ / 128), dim3(256), 0, stream>>>(xn, wbuf, Bias[0], T2, Bm2, cosb, sinb, qr, 1);
  conv(1); lora(1, xn, H_, H_);
  k_gemm_qkv<<<dim3(NH_, M_ / 128), dim3(256), 0, stream>>>(xn, wbuf, Bias[1], T2, Bm2, cosb, sinb, kr, 1);
  conv(2); lora(2, xn, H_, H_);
  k_gemm_qkv<<<dim3(NH_, M_ / 128), dim3(256), 0, stream>>>(xn, wbuf, Bias[2], T2, Bm2, cosb, sinb, vr, 0);
  // 3. attention -> attb [B,S,H] bf16 (aliases xn; xn1 dead)
  k_attn<<<dim3(B_ * NH_ * (S_ / 16)), dim3(256), 0, stream>>>(qr, kr, vr, attb);
  // 4. O projection + residual(x) -> xmed fp32
  conv(3); lora(3, attb, H_, H_);
  k_gemm<<<dim3(H_ / 128, M_ / 128), dim3(256), 0, stream>>>(
      attb, wbuf, Bias[3], T2, Bm2, x, nullptr, 0, xmed, nullptr, H_, H_);
  // 5. RMSNorm 2 -> xn
  k_rmsnorm<<<dim3(M_), dim3(256), 0, stream>>>(xmed, nw2, xn);
  // 6. gate -> silu(gate) bf16
  conv(4); lora(4, xn, H_, INTER_);
  k_gemm<<<dim3(INTER_ / 128, M_ / 128), dim3(256), 0, stream>>>(
      xn, wbuf, Bias[4], T2, Bm2, nullptr, nullptr, 1, nullptr, gact, INTER_, H_);
  // 7. up * silu(gate) -> gact in place
  conv(5); lora(5, xn, H_, INTER_);
  k_gemm<<<dim3(INTER_ / 128, M_ / 128), dim3(256), 0, stream>>>(
      xn, wbuf, Bias[5], T2, Bm2, nullptr, gact, 0, nullptr, gact, INTER_, H_);
  // 8. down + residual(xmed) -> d_out fp32
  conv(6); lora(6, gact, INTER_, H_);
  k_gemm<<<dim3(H_ / 128, M_ / 128), dim3(256), 0, stream>>>(
      gact, wbuf, Bias[6], T2, Bm2, xmed, nullptr, 0, outp, nullptr, H_, INTER_);
}

// Round 4
// 1981.761 us; speedup vs baseline: 1.9805x; 1.5121x over previous
//
#include <hip/hip_runtime.h>
#include <hip/hip_bf16.h>

// Fused Llama layer: B=2 S=2048 H=2048 NH=16 HD=128 INTER=5504 R=16
#define B_ 2
#define S_ 2048
#define H_ 2048
#define NH_ 16
#define HD_ 128
#define INTER_ 5504
#define M_ (B_*S_)

using bf16x8 = __attribute__((ext_vector_type(8))) short;
using f32x4  = __attribute__((ext_vector_type(4))) float;

__device__ __forceinline__ float b2f(unsigned short u) {
  union { unsigned u; float f; } c; c.u = ((unsigned)u) << 16; return c.f;
}
__device__ __forceinline__ short f2b(float f) {
  union { float f; unsigned u; } c; c.f = f;
  unsigned r = (c.u + 0x7fffu + ((c.u >> 16) & 1u)) >> 16;
  return (short)r;
}

typedef const __attribute__((address_space(1))) void* gvp;
typedef __attribute__((address_space(3))) void* lvp;
__device__ __forceinline__ void gl2lds16(const short* g, short* l) {
  __builtin_amdgcn_global_load_lds((gvp)g, (lvp)l, 16, 0, 0);
}

// ---------------- fp32 -> bf16 weight convert (vectorized) ----------------
__global__ void k_f2b(const float* __restrict__ in, short* __restrict__ out, int n) {
  int i = (blockIdx.x * 256 + threadIdx.x) * 4;
  if (i < n) {
    float4 f = *(const float4*)(in + i);
    short4 o4; o4.x = f2b(f.x); o4.y = f2b(f.y); o4.z = f2b(f.z); o4.w = f2b(f.w);
    *(short4*)(out + i) = o4;
  }
}

// ---------------- RMSNorm (fp32 in, bf16 out) ----------------
__global__ __launch_bounds__(256) void k_rmsnorm(const float* __restrict__ x,
                                                 const float* __restrict__ w,
                                                 short* __restrict__ out) {
  int row = blockIdx.x;
  const float4* xr = (const float4*)(x + (long)row * H_);
  float ss = 0.f;
  float4 v[2];
#pragma unroll
  for (int it = 0; it < 2; ++it) {
    float4 t = xr[threadIdx.x + it * 256];
    v[it] = t;
    ss += t.x*t.x + t.y*t.y + t.z*t.z + t.w*t.w;
  }
#pragma unroll
  for (int o = 32; o; o >>= 1) ss += __shfl_xor(ss, o);
  __shared__ float s4[4];
  if ((threadIdx.x & 63) == 0) s4[threadIdx.x >> 6] = ss;
  __syncthreads();
  float r = rsqrtf((s4[0] + s4[1] + s4[2] + s4[3]) * (1.f / H_) + 1e-5f);
  const float4* wr = (const float4*)w;
  short4* orow = (short4*)(out + (long)row * H_);
#pragma unroll
  for (int it = 0; it < 2; ++it) {
    float4 t = v[it];
    float4 ww = wr[threadIdx.x + it * 256];
    short4 o4;
    o4.x = f2b(t.x * r * ww.x); o4.y = f2b(t.y * r * ww.y);
    o4.z = f2b(t.z * r * ww.z); o4.w = f2b(t.w * r * ww.w);
    orow[threadIdx.x + it * 256] = o4;
  }
}

// ---------------- LoRA T = Xn @ A^T ----------------
__global__ __launch_bounds__(256) void k_lora_t(const short* __restrict__ Xn,
                                                const float* __restrict__ A,
                                                short* __restrict__ T2, int K) {
  int m = blockIdx.x;
  int g = threadIdx.x & 15;
  int r = threadIdx.x >> 4;
  const short* xr = Xn + (long)m * K;
  const float* ar = A + (long)r * K;
  float p = 0.f;
  for (int k = g; k < K; k += 16) p += b2f((unsigned short)xr[k]) * ar[k];
  __shared__ float red[256];
  red[threadIdx.x] = p;
  __syncthreads();
  if (threadIdx.x < 32) {
    float s = 0.f;
    if (threadIdx.x < 16) {
      int rr = threadIdx.x;
#pragma unroll
      for (int gg = 0; gg < 16; ++gg) s += red[rr * 16 + gg];
    }
    T2[(long)m * 32 + threadIdx.x] = (threadIdx.x < 16) ? f2b(s) : (short)0;
  }
}

// ---------------- Bm [N,16] fp32 -> Bm2 [N,32] bf16 zero-padded ----------------
__global__ void k_prep_bm2(const float* __restrict__ Bm, short* __restrict__ Bm2, int N) {
  int i = blockIdx.x * 256 + threadIdx.x;
  if (i >= N * 32) return;
  int c = i & 31, n = i >> 5;
  Bm2[i] = (c < 16) ? f2b(Bm[(long)n * 16 + c]) : (short)0;
}

// ---------------- QKV GEMM (LDS-staged) + RoPE + transpose ----------------
__global__ __launch_bounds__(256) void k_gemm_qkv(
    const short* __restrict__ A, const short* __restrict__ W,
    const float* __restrict__ bias,
    const short* __restrict__ T2, const short* __restrict__ Bm2,
    const float* __restrict__ cs, const float* __restrict__ sn,
    short* __restrict__ out, int do_rope) {
  const int K = H_;
  __shared__ short As[128 * 32];
  __shared__ short Bs[128 * 32];
  int t = threadIdx.x;
  int lane = t & 63, wave = t >> 6;
  int row0 = blockIdx.y * 128;
  int col0 = blockIdx.x * 128;
  int lr = lane & 15, lk = (lane >> 4) << 3;
  int srow = t >> 2, skc = t & 3;
  const short* Ag0 = A + (long)(row0 + srow) * K + skc * 8;
  const short* Ag1 = A + (long)(row0 + 64 + srow) * K + skc * 8;
  const short* Wg0 = W + (long)(col0 + srow) * K + skc * 8;
  const short* Wg1 = W + (long)(col0 + 64 + srow) * K + skc * 8;
  short* Al0 = As + wave * 512;
  short* Al1 = As + 2048 + wave * 512;
  short* Bl0 = Bs + wave * 512;
  short* Bl1 = Bs + 2048 + wave * 512;
  f32x4 acc[2][8] = {};
  for (int k0 = 0; k0 < K; k0 += 32) {
    gl2lds16(Ag0 + k0, Al0);
    gl2lds16(Ag1 + k0, Al1);
    gl2lds16(Wg0 + k0, Bl0);
    gl2lds16(Wg1 + k0, Bl1);
    __syncthreads();
    bf16x8 a[2], b[8];
#pragma unroll
    for (int i = 0; i < 2; ++i) a[i] = *(const bf16x8*)(As + (wave * 32 + i * 16 + lr) * 32 + lk);
#pragma unroll
    for (int j = 0; j < 8; ++j) b[j] = *(const bf16x8*)(Bs + (j * 16 + lr) * 32 + lk);
#pragma unroll
    for (int i = 0; i < 2; ++i)
#pragma unroll
      for (int j = 0; j < 8; ++j)
        acc[i][j] = __builtin_amdgcn_mfma_f32_16x16x32_bf16(a[i], b[j], acc[i][j], 0, 0, 0);
    __syncthreads();
  }
  { // LoRA K-extension
    bf16x8 a[2], b[8];
#pragma unroll
    for (int i = 0; i < 2; ++i) a[i] = *(const bf16x8*)(T2 + (long)(row0 + wave * 32 + i * 16 + lr) * 32 + lk);
#pragma unroll
    for (int j = 0; j < 8; ++j) b[j] = *(const bf16x8*)(Bm2 + (long)(col0 + j * 16 + lr) * 32 + lk);
#pragma unroll
    for (int i = 0; i < 2; ++i)
#pragma unroll
      for (int j = 0; j < 8; ++j)
        acc[i][j] = __builtin_amdgcn_mfma_f32_16x16x32_bf16(a[i], b[j], acc[i][j], 0, 0, 0);
  }
  int rquad = (lane >> 4) * 4;
  int head = blockIdx.x;
#pragma unroll
  for (int i = 0; i < 2; ++i) {
#pragma unroll
    for (int tt = 0; tt < 4; ++tt) {
      int row = row0 + wave * 32 + i * 16 + rquad + tt;
      int bb = row >> 11, sr = row & (S_ - 1);
      float vals[8];
#pragma unroll
      for (int j = 0; j < 8; ++j) vals[j] = acc[i][j][tt] + bias[col0 + j * 16 + lr];
      long obase = ((long)(bb * NH_ + head) * S_ + sr) * HD_;
      if (do_rope) {
#pragma unroll
        for (int j = 0; j < 8; ++j) {
          int d = j * 16 + lr;
          float rot = (j < 4) ? -vals[j + 4] : vals[j - 4];
          out[obase + d] = f2b(vals[j] * cs[sr * HD_ + d] + rot * sn[sr * HD_ + d]);
        }
      } else {
#pragma unroll
        for (int j = 0; j < 8; ++j) out[obase + j * 16 + lr] = f2b(vals[j]);
      }
    }
  }
}

// ---------------- General GEMM (LDS-staged) ----------------
__global__ __launch_bounds__(256) void k_gemm(
    const short* __restrict__ A, const short* __restrict__ W,
    const float* __restrict__ bias,
    const short* __restrict__ T2, const short* __restrict__ Bm2,
    const float* __restrict__ resid, const short* gatebf, int do_silu,
    float* __restrict__ outf, short* outb,
    int N, int K) {
  __shared__ short As[128 * 32];
  __shared__ short Bs[128 * 32];
  int t = threadIdx.x;
  int lane = t & 63, wave = t >> 6;
  int wm = wave >> 1, wn = wave & 1;
  int row0 = blockIdx.y * 128;
  int col0 = blockIdx.x * 128;
  int lr = lane & 15, lk = (lane >> 4) << 3;
  int srow = t >> 2, skc = t & 3;
  const short* Ag0 = A + (long)(row0 + srow) * K + skc * 8;
  const short* Ag1 = A + (long)(row0 + 64 + srow) * K + skc * 8;
  const short* Wg0 = W + (long)(col0 + srow) * K + skc * 8;
  const short* Wg1 = W + (long)(col0 + 64 + srow) * K + skc * 8;
  short* Al0 = As + wave * 512;
  short* Al1 = As + 2048 + wave * 512;
  short* Bl0 = Bs + wave * 512;
  short* Bl1 = Bs + 2048 + wave * 512;
  f32x4 acc[4][4] = {};
  for (int k0 = 0; k0 < K; k0 += 32) {
    gl2lds16(Ag0 + k0, Al0);
    gl2lds16(Ag1 + k0, Al1);
    gl2lds16(Wg0 + k0, Bl0);
    gl2lds16(Wg1 + k0, Bl1);
    __syncthreads();
    bf16x8 a[4], b[4];
#pragma unroll
    for (int i = 0; i < 4; ++i) a[i] = *(const bf16x8*)(As + (wm * 64 + i * 16 + lr) * 32 + lk);
#pragma unroll
    for (int j = 0; j < 4; ++j) b[j] = *(const bf16x8*)(Bs + (wn * 64 + j * 16 + lr) * 32 + lk);
#pragma unroll
    for (int i = 0; i < 4; ++i)
#pragma unroll
      for (int j = 0; j < 4; ++j)
        acc[i][j] = __builtin_amdgcn_mfma_f32_16x16x32_bf16(a[i], b[j], acc[i][j], 0, 0, 0);
    __syncthreads();
  }
  { // LoRA K-extension
    bf16x8 a[4], b[4];
#pragma unroll
    for (int i = 0; i < 4; ++i) a[i] = *(const bf16x8*)(T2 + (long)(row0 + wm * 64 + i * 16 + lr) * 32 + lk);
#pragma unroll
    for (int j = 0; j < 4; ++j) b[j] = *(const bf16x8*)(Bm2 + (long)(col0 + wn * 64 + j * 16 + lr) * 32 + lk);
#pragma unroll
    for (int i = 0; i < 4; ++i)
#pragma unroll
      for (int j = 0; j < 4; ++j)
        acc[i][j] = __builtin_amdgcn_mfma_f32_16x16x32_bf16(a[i], b[j], acc[i][j], 0, 0, 0);
  }
  int rquad = (lane >> 4) * 4;
#pragma unroll
  for (int i = 0; i < 4; ++i) {
#pragma unroll
    for (int j = 0; j < 4; ++j) {
      int col = col0 + wn * 64 + j * 16 + lr;
      float bc = bias[col];
#pragma unroll
      for (int tt = 0; tt < 4; ++tt) {
        int row = row0 + wm * 64 + i * 16 + rquad + tt;
        long idx = (long)row * N + col;
        float v2 = acc[i][j][tt] + bc;
        if (do_silu) v2 = v2 / (1.f + __expf(-v2));
        if (gatebf) v2 *= b2f((unsigned short)gatebf[idx]);
        if (resid) v2 += resid[idx];
        if (outf) outf[idx] = v2;
        else outb[idx] = f2b(v2);
      }
    }
  }
}

// ---------------- V transpose: [bh][s][d] -> [bh][d][s] (bf16) ----------------
__global__ __launch_bounds__(256) void k_vtrans(const short* __restrict__ in,
                                                short* __restrict__ out) {
  __shared__ short tb[64][72];
  int t = threadIdx.x;
  int s0 = blockIdx.x * 64, d0 = blockIdx.y * 64, bh = blockIdx.z;
  long ibase = (long)bh * S_ * HD_;
  long obase = (long)bh * HD_ * S_;
  int r = t >> 2, c = t & 3;
#pragma unroll
  for (int cc = 0; cc < 2; ++cc) {
    int ch = c + cc * 4;
    *(uint4*)&tb[r][ch * 8] = *(const uint4*)(in + ibase + (long)(s0 + r) * HD_ + d0 + ch * 8);
  }
  __syncthreads();
  int d = t >> 2;
#pragma unroll
  for (int cc = 0; cc < 2; ++cc) {
    int ch = c + cc * 4;
    short v[8];
#pragma unroll
    for (int ii = 0; ii < 8; ++ii) v[ii] = tb[ch * 8 + ii][d];
    *(uint4*)(out + obase + (long)(d0 + d) * S_ + s0 + ch * 8) = *(uint4*)v;
  }
}

// ---------------- MFMA flash attention (causal) ----------------
// block = (bh, 128 q-rows); 4 waves x 32 q-rows; K-tiles of 64 keys.
// S=Q*K^T via mfma (A=Q from global, B=K k-major LDS); softmax online in raw
// domain (scale folded into exp2); P->LDS; O^T[d][q] = V^T * P via mfma.
__global__ __launch_bounds__(256) void k_attn(const short* __restrict__ Q,
                                              const short* __restrict__ Kg,
                                              const short* __restrict__ Vt,
                                              short* __restrict__ att) {
  __shared__ __align__(16) short Kls[4][64 * 32];   // [ks][key][32]
  __shared__ __align__(16) short Vls[2][128 * 32];  // [kv][d][32]
  __shared__ __align__(16) short Pl[4][32 * 72];    // per-wave [q][72]
  __shared__ float al[4][32];
  __shared__ float ll[4][32];
  int t = threadIdx.x, lane = t & 63, wave = t >> 6;
  int lr = lane & 15, quad = lane >> 4;
  int qb = blockIdx.x & 15;
  int bh = blockIdx.x >> 4;
  int q0 = qb * 128;
  int qlo = q0 + wave * 32;
  long base = (long)bh * S_ * HD_;
  long vbase = (long)bh * HD_ * S_;
  const float c1 = 0.08838834764831845f * 1.44269504089f;  // scale*log2e
  // Q fragments (registers, once per block)
  bf16x8 qf[2][4];
#pragma unroll
  for (int i = 0; i < 2; ++i)
#pragma unroll
    for (int ks = 0; ks < 4; ++ks)
      qf[i][ks] = *(const bf16x8*)(Q + base + (long)(qlo + i * 16 + lr) * HD_ + ks * 32 + quad * 8);
  f32x4 oacc[8][2] = {};
  float m_i[2][4], l_i[2][4];
#pragma unroll
  for (int i = 0; i < 2; ++i)
#pragma unroll
    for (int tt = 0; tt < 4; ++tt) { m_i[i][tt] = -3.0e38f; l_i[i][tt] = 0.f; }
  int sk_row = lane >> 2, sk_c = lane & 3;
  int kbmax = (q0 + 127) >> 6;
  for (int kb = 0; kb <= kbmax; ++kb) {
    int kk0 = kb << 6;
    // stage K tile k-major: wave handles ks=wave
#pragma unroll
    for (int i = 0; i < 4; ++i)
      gl2lds16(Kg + base + (long)(kk0 + i * 16 + sk_row) * HD_ + wave * 32 + sk_c * 8,
               &Kls[wave][i * 512]);
    // stage V^T tile k-major: wave handles d-range wave*32..+31
#pragma unroll
    for (int kv = 0; kv < 2; ++kv)
#pragma unroll
      for (int db = 0; db < 2; ++db)
        gl2lds16(Vt + vbase + (long)(wave * 32 + db * 16 + sk_row) * S_ + kk0 + kv * 32 + sk_c * 8,
                 &Vls[kv][(wave * 32 + db * 16) * 32]);
    __syncthreads();
    if (kk0 <= qlo + 31) {
      // S = Q K^T
      f32x4 s[2][4] = {};
#pragma unroll
      for (int ks = 0; ks < 4; ++ks) {
        bf16x8 kf[4];
#pragma unroll
        for (int j = 0; j < 4; ++j) kf[j] = *(const bf16x8*)&Kls[ks][(j * 16 + lr) * 32 + quad * 8];
#pragma unroll
        for (int i = 0; i < 2; ++i)
#pragma unroll
          for (int j = 0; j < 4; ++j)
            s[i][j] = __builtin_amdgcn_mfma_f32_16x16x32_bf16(qf[i][ks], kf[j], s[i][j], 0, 0, 0);
      }
      // causal mask (only diagonal-region tiles)
      if (kk0 + 63 > qlo) {
#pragma unroll
        for (int i = 0; i < 2; ++i)
#pragma unroll
          for (int j = 0; j < 4; ++j) {
            int key = kk0 + j * 16 + lr;
#pragma unroll
            for (int tt = 0; tt < 4; ++tt) {
              int qrow = qlo + i * 16 + quad * 4 + tt;
              if (key > qrow) s[i][j][tt] = -1.0e30f;
            }
          }
      }
      // online softmax per row (raw domain, scale in exp2 args)
#pragma unroll
      for (int i = 0; i < 2; ++i) {
#pragma unroll
        for (int tt = 0; tt < 4; ++tt) {
          float mx = fmaxf(fmaxf(s[i][0][tt], s[i][1][tt]), fmaxf(s[i][2][tt], s[i][3][tt]));
#pragma unroll
          for (int o = 1; o < 16; o <<= 1) mx = fmaxf(mx, __shfl_xor(mx, o));
          float mold = m_i[i][tt];
          float mnew = fmaxf(mold, mx);
          float alpha = exp2f((mold - mnew) * c1);
          float mc = mnew * c1;
          float rs = 0.f;
#pragma unroll
          for (int j = 0; j < 4; ++j) {
            float p = exp2f(s[i][j][tt] * c1 - mc);
            s[i][j][tt] = p;
            rs += p;
          }
#pragma unroll
          for (int o = 1; o < 16; o <<= 1) rs += __shfl_xor(rs, o);
          l_i[i][tt] = l_i[i][tt] * alpha + rs;
          m_i[i][tt] = mnew;
          if (lr == 0) al[wave][i * 16 + quad * 4 + tt] = alpha;
        }
      }
      // P -> LDS (bf16, padded rows)
#pragma unroll
      for (int i = 0; i < 2; ++i)
#pragma unroll
        for (int j = 0; j < 4; ++j)
#pragma unroll
          for (int tt = 0; tt < 4; ++tt)
            Pl[wave][(i * 16 + quad * 4 + tt) * 72 + j * 16 + lr] = f2b(s[i][j][tt]);
      // rescale O accumulator by alpha[q]
#pragma unroll
      for (int i2 = 0; i2 < 2; ++i2) {
        float aq = al[wave][i2 * 16 + lr];
#pragma unroll
        for (int mi = 0; mi < 8; ++mi) {
          oacc[mi][i2][0] *= aq; oacc[mi][i2][1] *= aq;
          oacc[mi][i2][2] *= aq; oacc[mi][i2][3] *= aq;
        }
      }
      // O^T += V^T * P   (A = V^T tile, B = P)
#pragma unroll
      for (int kv = 0; kv < 2; ++kv) {
        bf16x8 pf[2];
#pragma unroll
        for (int i2 = 0; i2 < 2; ++i2)
          pf[i2] = *(const bf16x8*)&Pl[wave][(i2 * 16 + lr) * 72 + kv * 32 + quad * 8];
#pragma unroll
        for (int mi = 0; mi < 8; ++mi) {
          bf16x8 vfr = *(const bf16x8*)&Vls[kv][(mi * 16 + lr) * 32 + quad * 8];
#pragma unroll
          for (int i2 = 0; i2 < 2; ++i2)
            oacc[mi][i2] = __builtin_amdgcn_mfma_f32_16x16x32_bf16(vfr, pf[i2], oacc[mi][i2], 0, 0, 0);
        }
      }
    }
    __syncthreads();
  }
  // epilogue: divide by l, store O[q][d] as short4 along d
#pragma unroll
  for (int i = 0; i < 2; ++i)
#pragma unroll
    for (int tt = 0; tt < 4; ++tt)
      if (lr == 0) ll[wave][i * 16 + quad * 4 + tt] = l_i[i][tt];
  int b = bh >> 4, h = bh & (NH_ - 1);
#pragma unroll
  for (int i2 = 0; i2 < 2; ++i2) {
    float inv = 1.f / ll[wave][i2 * 16 + lr];
    int q_abs = qlo + i2 * 16 + lr;
    long ob = ((long)(b * S_ + q_abs)) * H_ + h * HD_;
#pragma unroll
    for (int mi = 0; mi < 8; ++mi) {
      short4 o4;
      o4.x = f2b(oacc[mi][i2][0] * inv);
      o4.y = f2b(oacc[mi][i2][1] * inv);
      o4.z = f2b(oacc[mi][i2][2] * inv);
      o4.w = f2b(oacc[mi][i2][3] * inv);
      *(short4*)(att + ob + mi * 16 + quad * 4) = o4;
    }
  }
}

// ---------------- host ----------------
extern "C" void kernel_launch(void* const* d_in, const int* in_sizes, int n_in,
                              void* d_out, int out_size, void* d_ws, size_t ws_size,
                              hipStream_t stream) {
  const float* x    = (const float*)d_in[0];
  const float* nw1  = (const float*)d_in[1];
  const float* nw2  = (const float*)d_in[2];
  const float* cosb = (const float*)d_in[3];
  const float* sinb = (const float*)d_in[4];
  const float *W[7], *Bias[7], *La[7], *Lb[7];
  for (int p = 0; p < 7; ++p) {
    W[p]    = (const float*)d_in[5 + p * 4];
    Bias[p] = (const float*)d_in[6 + p * 4];
    La[p]   = (const float*)d_in[7 + p * 4];
    Lb[p]   = (const float*)d_in[8 + p * 4];
  }
  const int wsz[7] = {H_*H_, H_*H_, H_*H_, H_*H_, INTER_*H_, INTER_*H_, INTER_*H_};

  char* ws = (char*)d_ws;
  size_t off = 0;
  short* wbuf = (short*)(ws + off); off += (size_t)INTER_ * H_ * 2;
  short* T2   = (short*)(ws + off); off += (size_t)M_ * 32 * 2;
  short* Bm2  = (short*)(ws + off); off += (size_t)INTER_ * 32 * 2;
  short* xn   = (short*)(ws + off); off += (size_t)M_ * H_ * 2;
  char*  regC = ws + off;           off += (size_t)M_ * H_ * 2 * 3;
  short* gact = (short*)(ws + off); off += (size_t)M_ * INTER_ * 2;
  short* qr = (short*)regC;
  short* kr = (short*)(regC + (size_t)M_ * H_ * 2);
  short* vr = (short*)(regC + (size_t)M_ * H_ * 2 * 2);
  float* xmed = (float*)regC;
  short* vt   = gact;               // vt lifetime ends before gact starts
  short* attb = xn;
  float* outp = (float*)d_out;

  auto conv = [&](int p) {
    k_f2b<<<dim3((wsz[p] / 4 + 255) / 256), dim3(256), 0, stream>>>(W[p], wbuf, wsz[p]);
  };
  auto lora = [&](int p, const short* Ain, int K, int N) {
    k_lora_t<<<dim3(M_), dim3(256), 0, stream>>>(Ain, La[p], T2, K);
    k_prep_bm2<<<dim3((N * 32 + 255) / 256), dim3(256), 0, stream>>>(Lb[p], Bm2, N);
  };

  // 1. RMSNorm 1
  k_rmsnorm<<<dim3(M_), dim3(256), 0, stream>>>(x, nw1, xn);
  // 2. Q,K,V projections fused with RoPE + transpose -> [B,NH,S,HD]
  conv(0); lora(0, xn, H_, H_);
  k_gemm_qkv<<<dim3(NH_, M_ / 128), dim3(256), 0, stream>>>(xn, wbuf, Bias[0], T2, Bm2, cosb, sinb, qr, 1);
  conv(1); lora(1, xn, H_, H_);
  k_gemm_qkv<<<dim3(NH_, M_ / 128), dim3(256), 0, stream>>>(xn, wbuf, Bias[1], T2, Bm2, cosb, sinb, kr, 1);
  conv(2); lora(2, xn, H_, H_);
  k_gemm_qkv<<<dim3(NH_, M_ / 128), dim3(256), 0, stream>>>(xn, wbuf, Bias[2], T2, Bm2, cosb, sinb, vr, 0);
  // 3. V transpose -> vt [bh][d][s]
  k_vtrans<<<dim3(S_ / 64, HD_ / 64, B_ * NH_), dim3(256), 0, stream>>>(vr, vt);
  // 4. MFMA flash attention -> attb [B,S,H] bf16
  k_attn<<<dim3(B_ * NH_ * (S_ / 128)), dim3(256), 0, stream>>>(qr, kr, vt, attb);
  // 5. O projection + residual(x) -> xmed fp32
  conv(3); lora(3, attb, H_, H_);
  k_gemm<<<dim3(H_ / 128, M_ / 128), dim3(256), 0, stream>>>(
      attb, wbuf, Bias[3], T2, Bm2, x, nullptr, 0, xmed, nullptr, H_, H_);
  // 6. RMSNorm 2 -> xn
  k_rmsnorm<<<dim3(M_), dim3(256), 0, stream>>>(xmed, nw2, xn);
  // 7. gate -> silu(gate) bf16
  conv(4); lora(4, xn, H_, INTER_);
  k_gemm<<<dim3(INTER_ / 128, M_ / 128), dim3(256), 0, stream>>>(
      xn, wbuf, Bias[4], T2, Bm2, nullptr, nullptr, 1, nullptr, gact, INTER_, H_);
  // 8. up * silu(gate) -> gact in place
  conv(5); lora(5, xn, H_, INTER_);
  k_gemm<<<dim3(INTER_ / 128, M_ / 128), dim3(256), 0, stream>>>(
      xn, wbuf, Bias[5], T2, Bm2, nullptr, gact, 0, nullptr, gact, INTER_, H_);
  // 9. down + residual(xmed) -> d_out fp32
  conv(6); lora(6, gact, INTER_, H_);
  k_gemm<<<dim3(H_ / 128, M_ / 128), dim3(256), 0, stream>>>(
      gact, wbuf, Bias[6], T2, Bm2, xmed, nullptr, 0, outp, nullptr, H_, INTER_);
}